// Round 3
// baseline (497.228 us; speedup 1.0000x reference)
//
#include <hip/hip_runtime.h>

#define KDIM 1024
#define DDIM 64
#define SPAT 32768      // 32*32*32
#define NVEC 65536      // 2*SPAT
#define BLK  256
#define VPB  64         // rows per block
#define NCH  4          // k-chunks, one per wave
#define KCH  (KDIM/NCH)
#define KU   8

// Prevent fp contraction / refolding across this value.
__device__ __forceinline__ float opaque(float x) {
    asm volatile("" : "+v"(x));
    return x;
}

// Bitwise replica of np.add.reduce over 64 contiguous f32:
// seed = x[0]; pairwise 8-accumulator base case over x[1..63] (n=63):
//   r[j] = x[1+j] + x[9+j] + ... + x[49+j]   (7 sequential adds)
//   res  = ((r0+r1)+(r2+r3)) + ((r4+r5)+(r6+r7))
//   res += x[57..63] sequentially
//   return x[0] + res
__device__ __forceinline__ float np_sum64(const float q[DDIM]) {
    float r[8];
#pragma unroll
    for (int j = 0; j < 8; ++j) r[j] = q[1 + j];
#pragma unroll
    for (int i = 8; i < 56; i += 8) {
#pragma unroll
        for (int j = 0; j < 8; ++j) r[j] += q[1 + i + j];
    }
    float res = ((r[0] + r[1]) + (r[2] + r[3])) + ((r[4] + r[5]) + (r[6] + r[7]));
#pragma unroll
    for (int m = 57; m < 64; ++m) res += q[m];
    return q[0] + res;
}

// prep: h[k] = np-f32 sum of emb[k,:]**2 ; e2[k,d] = 2*emb[k,d] (exact)
__global__ void vq_prep_kernel(const float* __restrict__ emb,
                               float* __restrict__ e2, float* __restrict__ h) {
    int k = blockIdx.x * blockDim.x + threadIdx.x;
    if (k >= KDIM) return;
    float e[DDIM], q[DDIM];
#pragma unroll
    for (int d = 0; d < DDIM; ++d) {
        e[d] = emb[k * DDIM + d];
        q[d] = opaque(e[d] * e[d]);     // fl(e*e), kept un-fusable
        e2[k * DDIM + d] = e[d] + e[d]; // exact *2
    }
    h[k] = np_sum64(q);
}

__global__ __launch_bounds__(BLK, 4) void vq_main_kernel(
    const float* __restrict__ z, const float* __restrict__ emb,
    const float* __restrict__ e2, const float* __restrict__ h,
    float* __restrict__ out, float* __restrict__ loss, float* __restrict__ idxf)
{
    __shared__ float sb1[NCH][VPB];
    __shared__ int   si1[NCH][VPB];

    const int tid = threadIdx.x;
    const int v   = tid & (VPB - 1);
    const int c   = tid >> 6;
    const int n   = blockIdx.x * VPB + v;
    const int b   = n >> 15;
    const int s   = n & (SPAT - 1);
    const float* zp = z + (size_t)b * (DDIM * SPAT) + s;

    float zv[DDIM];
#pragma unroll
    for (int d = 0; d < DDIM; ++d) zv[d] = zp[(size_t)d * SPAT];

    // s_n exactly as numpy computes sum(flat**2, axis=1)
    float q[DDIM];
#pragma unroll
    for (int d = 0; d < DDIM; ++d) q[d] = opaque(zv[d] * zv[d]);
    const float sn = np_sum64(q);

    const int k0 = c * KCH;
    float b1 = 3.0e38f;
    int   i1 = 0;
    for (int kk = 0; kk < KCH; kk += KU) {
        const int kbase = k0 + kk;
        float acc[KU];
#pragma unroll
        for (int u = 0; u < KU; ++u) acc[u] = 0.0f;
#pragma unroll
        for (int d = 0; d < DDIM; ++d) {
            const float zd = zv[d];
#pragma unroll
            for (int u = 0; u < KU; ++u)
                acc[u] = fmaf(e2[(kbase + u) * DDIM + d], zd, acc[u]); // sgemm: sequential f32 FMA from 0
        }
#pragma unroll
        for (int u = 0; u < KU; ++u) {
            float t    = sn + h[kbase + u];   // fl(s + h)  (numpy s[:,None] + h[None,:])
            float dist = t - acc[u];          // fl(t - 2z.e) (numpy subtract)
            if (dist < b1) { b1 = dist; i1 = kbase + u; }  // strict <: first index wins
        }
    }
    sb1[c][v] = b1; si1[c][v] = i1;
    __syncthreads();

    if (c == 0) {
        float B1 = sb1[0][v];
        int   I1 = si1[0][v];
#pragma unroll
        for (int cc = 1; cc < NCH; ++cc) {
            float ob1 = sb1[cc][v];
            int   oi1 = si1[cc][v];
            if (ob1 < B1) { B1 = ob1; I1 = oi1; }  // ascending chunk, strict <: lowest index on ties
        }
        const float* e = emb + I1 * DDIM;
        float* op = out + (size_t)b * (DDIM * SPAT) + s;
        float lsum = 0.f;
#pragma unroll
        for (int d = 0; d < DDIM; ++d) {
            float qv = e[d];
            op[(size_t)d * SPAT] = qv;
            float df = qv - zv[d];
            lsum = fmaf(df, df, lsum);
        }
        idxf[n] = (float)I1;
#pragma unroll
        for (int off = 32; off > 0; off >>= 1)
            lsum += __shfl_down(lsum, off, 64);
        if (v == 0)
            atomicAdd(loss, lsum * (1.25f / 4194304.0f)); // (beta+1)*mean
    }
}

extern "C" void kernel_launch(void* const* d_in, const int* in_sizes, int n_in,
                              void* d_out, int out_size, void* d_ws, size_t ws_size,
                              hipStream_t stream) {
    const float* z   = (const float*)d_in[0];   // [2, 64, 32, 32, 32]
    const float* emb = (const float*)d_in[1];   // [1024, 64]
    float* out  = (float*)d_out;                // z_q | loss | indices
    float* loss = out + 4194304;
    float* idxf = out + 4194305;
    float* e2   = (float*)d_ws;                 // [1024*64] 2*emb
    float* h    = e2 + KDIM * DDIM;             // [1024] np-f32 ||e||^2

    hipMemsetAsync(loss, 0, sizeof(float), stream);
    vq_prep_kernel<<<KDIM / BLK, BLK, 0, stream>>>(emb, e2, h);
    vq_main_kernel<<<NVEC / VPB, BLK, 0, stream>>>(z, emb, e2, h, out, loss, idxf);
}

// Round 4
// 178.828 us; speedup vs baseline: 2.7805x; 2.7805x over previous
//
#include <hip/hip_runtime.h>

#define KDIM 1024
#define DDIM 64
#define SPAT 32768      // 32*32*32
#define NVEC 65536      // 2*SPAT
#define BLK  256
#define ROWS 128        // rows per block (waves 0,1 -> rows 0..63; waves 2,3 -> 64..127)
#define TK   128        // k-tile per round
#define NRND 4          // rounds: each half scans 4*128 = 512 k

__device__ __forceinline__ float opaque(float x) {
    asm volatile("" : "+v"(x));
    return x;
}

// Bitwise replica of np.add.reduce pairwise base case over fl(zv[d]^2), d=0..63
__device__ __forceinline__ float np_sumsq64(const float zv[DDIM]) {
    float r8[8];
#pragma unroll
    for (int j = 0; j < 8; ++j) r8[j] = opaque(zv[1 + j] * zv[1 + j]);
#pragma unroll
    for (int i = 8; i < 56; i += 8) {
#pragma unroll
        for (int j = 0; j < 8; ++j) r8[j] += opaque(zv[1 + i + j] * zv[1 + i + j]);
    }
    float res = ((r8[0] + r8[1]) + (r8[2] + r8[3])) + ((r8[4] + r8[5]) + (r8[6] + r8[7]));
#pragma unroll
    for (int m = 57; m < 64; ++m) res += opaque(zv[m] * zv[m]);
    return opaque(zv[0] * zv[0]) + res;
}

// prep: h[k] = np-f32 sum(emb[k,:]**2); e2[k,d] = 2*emb[k,d] (exact)
__global__ void vq_prep_kernel(const float* __restrict__ emb,
                               float* __restrict__ e2, float* __restrict__ h) {
    int k = blockIdx.x * blockDim.x + threadIdx.x;
    if (k >= KDIM) return;
    float e[DDIM];
#pragma unroll
    for (int d = 0; d < DDIM; ++d) {
        e[d] = emb[k * DDIM + d];
        e2[k * DDIM + d] = e[d] + e[d];
    }
    h[k] = np_sumsq64(e);
}

__global__ __launch_bounds__(BLK, 2) void vq_main_kernel(
    const float* __restrict__ z, const float* __restrict__ emb,
    const float* __restrict__ e2, const float* __restrict__ h,
    float* __restrict__ out, float* __restrict__ loss, float* __restrict__ idxf)
{
    __shared__ float lds_e[2 * TK * DDIM];   // [half][128][64]  64 KB
    __shared__ float lds_h[2 * TK];          // [half][128]
    __shared__ float sb1s[4][64];
    __shared__ int   si1s[4][64];

    const int tid  = threadIdx.x;
    const int lane = tid & 63;
    const int w    = tid >> 6;        // wave id 0..3
    const int half = w & 1;           // k-half this wave scans
    const int rg   = w >> 1;          // row group 0/1
    const int n    = blockIdx.x * ROWS + rg * 64 + lane;
    const int b    = n >> 15;
    const int s    = n & (SPAT - 1);
    const float* zp = z + (size_t)b * (DDIM * SPAT) + s;

    // z row in VGPRs
    float zv[DDIM];
#pragma unroll
    for (int d = 0; d < DDIM; ++d) zv[d] = zp[(size_t)d * SPAT];

    const float sn = np_sumsq64(zv);   // identical to numpy sum(flat**2, axis=1)

    const float* my_lds = lds_e + half * (TK * DDIM);
    float b1 = 3.0e38f;
    int   i1 = 0;

    for (int r = 0; r < NRND; ++r) {
        __syncthreads();
        // stage tiles for both halves: e2 rows [r*128, r*128+128) and [512+r*128, ...)
        {
            const float4* srcA = (const float4*)(e2 + (r * TK) * DDIM);
            const float4* srcB = (const float4*)(e2 + (512 + r * TK) * DDIM);
            float4* dst = (float4*)lds_e;
#pragma unroll
            for (int j = 0; j < 8; ++j) {
                dst[tid + j * BLK]            = srcA[tid + j * BLK];
                dst[2048 + tid + j * BLK]     = srcB[tid + j * BLK];
            }
            if (tid < 32)       ((float4*)lds_h)[tid]      = ((const float4*)(h + r * TK))[tid];
            else if (tid < 64)  ((float4*)lds_h)[tid]      = ((const float4*)(h + 512 + r * TK))[tid - 32];
        }
        __syncthreads();

        const int kg0 = half * 512 + r * TK;   // global k of tile row 0
        for (int kk = 0; kk < TK; kk += 4) {
            const float* ep = my_lds + kk * DDIM;
            float a0 = 0.f, a1 = 0.f, a2 = 0.f, a3 = 0.f;
#pragma unroll
            for (int dg = 0; dg < DDIM; dg += 4) {
                float4 e0 = *(const float4*)(ep + 0 * DDIM + dg);
                float4 e1 = *(const float4*)(ep + 1 * DDIM + dg);
                float4 ee2 = *(const float4*)(ep + 2 * DDIM + dg);
                float4 e3 = *(const float4*)(ep + 3 * DDIM + dg);
                // sequential ascending-d accumulation per k (bit-identical to passing R3 order)
                a0 = fmaf(e0.x, zv[dg], a0); a1 = fmaf(e1.x, zv[dg], a1);
                a2 = fmaf(ee2.x, zv[dg], a2); a3 = fmaf(e3.x, zv[dg], a3);
                a0 = fmaf(e0.y, zv[dg+1], a0); a1 = fmaf(e1.y, zv[dg+1], a1);
                a2 = fmaf(ee2.y, zv[dg+1], a2); a3 = fmaf(e3.y, zv[dg+1], a3);
                a0 = fmaf(e0.z, zv[dg+2], a0); a1 = fmaf(e1.z, zv[dg+2], a1);
                a2 = fmaf(ee2.z, zv[dg+2], a2); a3 = fmaf(e3.z, zv[dg+2], a3);
                a0 = fmaf(e0.w, zv[dg+3], a0); a1 = fmaf(e1.w, zv[dg+3], a1);
                a2 = fmaf(ee2.w, zv[dg+3], a2); a3 = fmaf(e3.w, zv[dg+3], a3);
            }
            const float* hp = lds_h + half * TK + kk;
            float d0 = (sn + hp[0]) - a0;
            float d1 = (sn + hp[1]) - a1;
            float d2 = (sn + hp[2]) - a2;
            float d3 = (sn + hp[3]) - a3;
            // strict <, ascending k: first index wins
            if (d0 < b1) { b1 = d0; i1 = kg0 + kk + 0; }
            if (d1 < b1) { b1 = d1; i1 = kg0 + kk + 1; }
            if (d2 < b1) { b1 = d2; i1 = kg0 + kk + 2; }
            if (d3 < b1) { b1 = d3; i1 = kg0 + kk + 3; }
        }
    }

    sb1s[w][lane] = b1;
    si1s[w][lane] = i1;
    __syncthreads();

    if (half == 0) {
        // merge with the k-half1 wave of the same row group; half0 wins ties (lower k)
        float ob = sb1s[w + 1][lane];
        int   oi = si1s[w + 1][lane];
        if (ob < b1) { b1 = ob; i1 = oi; }

        const float* e = emb + i1 * DDIM;
        float* op = out + (size_t)b * (DDIM * SPAT) + s;
        float lsum = 0.f;
#pragma unroll
        for (int d = 0; d < DDIM; ++d) {
            float qv = e[d];
            op[(size_t)d * SPAT] = qv;
            float df = qv - zv[d];
            lsum = fmaf(df, df, lsum);
        }
        idxf[n] = (float)i1;
#pragma unroll
        for (int off = 32; off > 0; off >>= 1)
            lsum += __shfl_down(lsum, off, 64);
        if (lane == 0)
            atomicAdd(loss, lsum * (1.25f / 4194304.0f)); // (beta+1)*mean
    }
}

extern "C" void kernel_launch(void* const* d_in, const int* in_sizes, int n_in,
                              void* d_out, int out_size, void* d_ws, size_t ws_size,
                              hipStream_t stream) {
    const float* z   = (const float*)d_in[0];   // [2, 64, 32, 32, 32]
    const float* emb = (const float*)d_in[1];   // [1024, 64]
    float* out  = (float*)d_out;                // z_q | loss | indices
    float* loss = out + 4194304;
    float* idxf = out + 4194305;
    float* e2   = (float*)d_ws;                 // [1024*64]
    float* h    = e2 + KDIM * DDIM;             // [1024]

    hipMemsetAsync(loss, 0, sizeof(float), stream);
    vq_prep_kernel<<<KDIM / BLK, BLK, 0, stream>>>(emb, e2, h);
    vq_main_kernel<<<NVEC / ROWS, BLK, 0, stream>>>(z, emb, e2, h, out, loss, idxf);
}

// Round 5
// 162.295 us; speedup vs baseline: 3.0637x; 1.1019x over previous
//
#include <hip/hip_runtime.h>

#define KDIM 1024
#define DDIM 64
#define SPAT 32768      // 32*32*32
#define NVEC 65536      // 2*SPAT
#define BLK  256
#define ROWS 256        // rows per block: 2 row-groups x 64 lanes x 2 rows/lane
#define TK   128        // k-tile per round per half
#define NRND 4          // rounds: each k-half scans 4*128 = 512 k

__device__ __forceinline__ float opaque(float x) {
    asm volatile("" : "+v"(x));
    return x;
}

// Bitwise replica of np.add.reduce pairwise base case over fl(zv[d]^2), d=0..63
__device__ __forceinline__ float np_sumsq64(const float zv[DDIM]) {
    float r8[8];
#pragma unroll
    for (int j = 0; j < 8; ++j) r8[j] = opaque(zv[1 + j] * zv[1 + j]);
#pragma unroll
    for (int i = 8; i < 56; i += 8) {
#pragma unroll
        for (int j = 0; j < 8; ++j) r8[j] += opaque(zv[1 + i + j] * zv[1 + i + j]);
    }
    float res = ((r8[0] + r8[1]) + (r8[2] + r8[3])) + ((r8[4] + r8[5]) + (r8[6] + r8[7]));
#pragma unroll
    for (int m = 57; m < 64; ++m) res += opaque(zv[m] * zv[m]);
    return opaque(zv[0] * zv[0]) + res;
}

// prep: h[k] = np-f32 sum(emb[k,:]**2); e2[k,d] = 2*emb[k,d] (exact)
__global__ void vq_prep_kernel(const float* __restrict__ emb,
                               float* __restrict__ e2, float* __restrict__ h) {
    int k = blockIdx.x * blockDim.x + threadIdx.x;
    if (k >= KDIM) return;
    float e[DDIM];
#pragma unroll
    for (int d = 0; d < DDIM; ++d) {
        e[d] = emb[k * DDIM + d];
        e2[k * DDIM + d] = e[d] + e[d];
    }
    h[k] = np_sumsq64(e);
}

__global__ __launch_bounds__(BLK, 2) void vq_main_kernel(
    const float* __restrict__ z, const float* __restrict__ emb,
    const float* __restrict__ e2, const float* __restrict__ h,
    float* __restrict__ out, float* __restrict__ loss, float* __restrict__ idxf)
{
    __shared__ float lds_e[2 * TK * DDIM];   // [half][128][64]  64 KB
    __shared__ float lds_h[2 * TK];          // [half][128]
    __shared__ float sb1a[4][64];
    __shared__ int   si1a[4][64];
    __shared__ float sb1b[4][64];
    __shared__ int   si1b[4][64];

    const int tid  = threadIdx.x;
    const int lane = tid & 63;
    const int w    = tid >> 6;        // wave id 0..3
    const int half = w & 1;           // k-half this wave scans
    const int rg   = w >> 1;          // row group 0/1
    const int n0   = blockIdx.x * ROWS + rg * 64 + lane;   // row A
    const int n1   = n0 + 128;                             // row B
    const int b0   = n0 >> 15, s0 = n0 & (SPAT - 1);
    const int b1r  = n1 >> 15, s1 = n1 & (SPAT - 1);
    const float* zp0 = z + (size_t)b0 * (DDIM * SPAT) + s0;
    const float* zp1 = z + (size_t)b1r * (DDIM * SPAT) + s1;

    // two z rows in VGPRs
    float zv0[DDIM], zv1[DDIM];
#pragma unroll
    for (int d = 0; d < DDIM; ++d) zv0[d] = zp0[(size_t)d * SPAT];
#pragma unroll
    for (int d = 0; d < DDIM; ++d) zv1[d] = zp1[(size_t)d * SPAT];

    const float sn0 = np_sumsq64(zv0);   // identical to numpy sum(flat**2, axis=1)
    const float sn1 = np_sumsq64(zv1);

    const float* my_lds = lds_e + half * (TK * DDIM);
    float bA = 3.0e38f, bB = 3.0e38f;
    int   iA = 0,       iB = 0;

    for (int r = 0; r < NRND; ++r) {
        __syncthreads();
        {
            const float4* srcA = (const float4*)(e2 + (r * TK) * DDIM);
            const float4* srcB = (const float4*)(e2 + (512 + r * TK) * DDIM);
            float4* dst = (float4*)lds_e;
#pragma unroll
            for (int j = 0; j < 8; ++j) {
                dst[tid + j * BLK]        = srcA[tid + j * BLK];
                dst[2048 + tid + j * BLK] = srcB[tid + j * BLK];
            }
            if (tid < 32)       ((float4*)lds_h)[tid] = ((const float4*)(h + r * TK))[tid];
            else if (tid < 64)  ((float4*)lds_h)[tid] = ((const float4*)(h + 512 + r * TK))[tid - 32];
        }
        __syncthreads();

        const int kg0 = half * 512 + r * TK;
        for (int kk = 0; kk < TK; kk += 4) {
            const float* ep = my_lds + kk * DDIM;
            float a00 = 0.f, a10 = 0.f, a20 = 0.f, a30 = 0.f;  // row A, k+0..3
            float a01 = 0.f, a11 = 0.f, a21 = 0.f, a31 = 0.f;  // row B, k+0..3
#pragma unroll
            for (int dg = 0; dg < DDIM; dg += 4) {
                float4 e0 = *(const float4*)(ep + 0 * DDIM + dg);
                float4 e1 = *(const float4*)(ep + 1 * DDIM + dg);
                float4 eX = *(const float4*)(ep + 2 * DDIM + dg);
                float4 e3 = *(const float4*)(ep + 3 * DDIM + dg);
                // sequential ascending-d accumulation per (row,k): bit-identical chains
                float za, zb;
                za = zv0[dg];   zb = zv1[dg];
                a00 = fmaf(e0.x, za, a00); a01 = fmaf(e0.x, zb, a01);
                a10 = fmaf(e1.x, za, a10); a11 = fmaf(e1.x, zb, a11);
                a20 = fmaf(eX.x, za, a20); a21 = fmaf(eX.x, zb, a21);
                a30 = fmaf(e3.x, za, a30); a31 = fmaf(e3.x, zb, a31);
                za = zv0[dg+1]; zb = zv1[dg+1];
                a00 = fmaf(e0.y, za, a00); a01 = fmaf(e0.y, zb, a01);
                a10 = fmaf(e1.y, za, a10); a11 = fmaf(e1.y, zb, a11);
                a20 = fmaf(eX.y, za, a20); a21 = fmaf(eX.y, zb, a21);
                a30 = fmaf(e3.y, za, a30); a31 = fmaf(e3.y, zb, a31);
                za = zv0[dg+2]; zb = zv1[dg+2];
                a00 = fmaf(e0.z, za, a00); a01 = fmaf(e0.z, zb, a01);
                a10 = fmaf(e1.z, za, a10); a11 = fmaf(e1.z, zb, a11);
                a20 = fmaf(eX.z, za, a20); a21 = fmaf(eX.z, zb, a21);
                a30 = fmaf(e3.z, za, a30); a31 = fmaf(e3.z, zb, a31);
                za = zv0[dg+3]; zb = zv1[dg+3];
                a00 = fmaf(e0.w, za, a00); a01 = fmaf(e0.w, zb, a01);
                a10 = fmaf(e1.w, za, a10); a11 = fmaf(e1.w, zb, a11);
                a20 = fmaf(eX.w, za, a20); a21 = fmaf(eX.w, zb, a21);
                a30 = fmaf(e3.w, za, a30); a31 = fmaf(e3.w, zb, a31);
            }
            const float* hp = lds_h + half * TK + kk;
            float h0 = hp[0], h1 = hp[1], h2 = hp[2], h3 = hp[3];
            const int kb = kg0 + kk;
            // row A
            float dA0 = (sn0 + h0) - a00, dA1 = (sn0 + h1) - a10;
            float dA2 = (sn0 + h2) - a20, dA3 = (sn0 + h3) - a30;
            if (dA0 < bA) { bA = dA0; iA = kb + 0; }
            if (dA1 < bA) { bA = dA1; iA = kb + 1; }
            if (dA2 < bA) { bA = dA2; iA = kb + 2; }
            if (dA3 < bA) { bA = dA3; iA = kb + 3; }
            // row B
            float dB0 = (sn1 + h0) - a01, dB1 = (sn1 + h1) - a11;
            float dB2 = (sn1 + h2) - a21, dB3 = (sn1 + h3) - a31;
            if (dB0 < bB) { bB = dB0; iB = kb + 0; }
            if (dB1 < bB) { bB = dB1; iB = kb + 1; }
            if (dB2 < bB) { bB = dB2; iB = kb + 2; }
            if (dB3 < bB) { bB = dB3; iB = kb + 3; }
        }
    }

    sb1a[w][lane] = bA; si1a[w][lane] = iA;
    sb1b[w][lane] = bB; si1b[w][lane] = iB;
    __syncthreads();

    if (half == 0) {
        // merge with k-half1 wave of same row group; half0 wins ties (lower k)
        {
            float ob = sb1a[w + 1][lane]; int oi = si1a[w + 1][lane];
            if (ob < bA) { bA = ob; iA = oi; }
        }
        {
            float ob = sb1b[w + 1][lane]; int oi = si1b[w + 1][lane];
            if (ob < bB) { bB = ob; iB = oi; }
        }

        float lsum = 0.f;
        {
            const float* e = emb + iA * DDIM;
            float* op = out + (size_t)b0 * (DDIM * SPAT) + s0;
#pragma unroll
            for (int d = 0; d < DDIM; ++d) {
                float qv = e[d];
                op[(size_t)d * SPAT] = qv;
                float df = qv - zv0[d];
                lsum = fmaf(df, df, lsum);
            }
            idxf[n0] = (float)iA;
        }
        {
            const float* e = emb + iB * DDIM;
            float* op = out + (size_t)b1r * (DDIM * SPAT) + s1;
#pragma unroll
            for (int d = 0; d < DDIM; ++d) {
                float qv = e[d];
                op[(size_t)d * SPAT] = qv;
                float df = qv - zv1[d];
                lsum = fmaf(df, df, lsum);
            }
            idxf[n1] = (float)iB;
        }
#pragma unroll
        for (int off = 32; off > 0; off >>= 1)
            lsum += __shfl_down(lsum, off, 64);
        if (lane == 0)
            atomicAdd(loss, lsum * (1.25f / 4194304.0f)); // (beta+1)*mean
    }
}

extern "C" void kernel_launch(void* const* d_in, const int* in_sizes, int n_in,
                              void* d_out, int out_size, void* d_ws, size_t ws_size,
                              hipStream_t stream) {
    const float* z   = (const float*)d_in[0];   // [2, 64, 32, 32, 32]
    const float* emb = (const float*)d_in[1];   // [1024, 64]
    float* out  = (float*)d_out;                // z_q | loss | indices
    float* loss = out + 4194304;
    float* idxf = out + 4194305;
    float* e2   = (float*)d_ws;                 // [1024*64]
    float* h    = e2 + KDIM * DDIM;             // [1024]

    hipMemsetAsync(loss, 0, sizeof(float), stream);
    vq_prep_kernel<<<KDIM / BLK, BLK, 0, stream>>>(emb, e2, h);
    vq_main_kernel<<<NVEC / ROWS, BLK, 0, stream>>>(z, emb, e2, h, out, loss, idxf);
}